// Round 2
// 674.036 us; speedup vs baseline: 1.0424x; 1.0424x over previous
//
#include <hip/hip_runtime.h>
#include <math.h>

// Problem constants (from reference setup_inputs): n=16, b=4, t=2048, h=1024
#define H     1024
#define NBLK  16
#define BT    8192                 // b * t
#define ROUTED_SIZE (BT * H)       // 8,388,608 floats
#define SCALE_INV (1.0f / 32.0f)   // 1 / (sqrt(1024) * BASE_TAU)

typedef float v4f __attribute__((ext_vector_type(4)));

// ---------------------------------------------------------------------------
// Pre-kernel: qb[n] = sum_h w_query[pos][h] * key_pos_bias[n][h]  (n = 0..15)
// ---------------------------------------------------------------------------
__global__ __launch_bounds__(1024) void qb_kernel(
    const float* __restrict__ w_query,
    const float* __restrict__ key_pos_bias,
    const int*   __restrict__ pos_p,
    float*       __restrict__ qb)
{
    const int n    = threadIdx.x >> 6;   // wave id = history slot
    const int lane = threadIdx.x & 63;
    const int pos  = *pos_p;

    const float* q = w_query      + (size_t)pos * H;
    const float* b = key_pos_bias + (size_t)n   * H;

    float s = 0.0f;
#pragma unroll
    for (int j = 0; j < 4; ++j) {
        const int h = lane * 16 + j * 4;
        const float4 qv = *(const float4*)(q + h);
        const float4 bv = *(const float4*)(b + h);
        s += qv.x * bv.x + qv.y * bv.y + qv.z * bv.z + qv.w * bv.w;
    }
#pragma unroll
    for (int off = 32; off; off >>= 1) s += __shfl_xor(s, off, 64);
    if (lane == 0) qb[n] = s;
}

// ---------------------------------------------------------------------------
// Main kernel: one 256-thread block per (b,t) column; thread owns 4 h-elems.
// v3 changes vs v2:
//   - reduction via LDS transpose: 16 ds_write_b64 + 16 ds_read_b64 + 4-level
//     shuffle per thread (was 192 ds_bpermute with 6-deep dependent chains)
//   - scores live in LDS (pv[n][0].x); the alpha tail store indexes LDS, not a
//     runtime-indexed register array (avoids scratch demotion / movrel waterfall)
//   - nontemporal loads/stores for the single-use streaming data
//   - LDS exactly 32 KiB/block -> 4 blocks/CU within the 160 KiB budget
// values is still read from HBM exactly once.
// ---------------------------------------------------------------------------
__global__ __launch_bounds__(256, 4) void block_attn_res_kernel(
    const float* __restrict__ values,   // [16, 4, 2048, 1024]
    const float* __restrict__ w_query,  // [24, 1024]
    const int*   __restrict__ pos_p,    // scalar (16)
    const float* __restrict__ qb,       // [16] precomputed q·bias
    float*       __restrict__ out)      // routed [4,2048,1024] ++ alpha [4,2048,16]
{
    const int bt  = blockIdx.x;        // 0..8191
    const int tid = threadIdx.x;       // 0..255
    const int h0  = tid << 2;

    const int pos = *pos_p;
    const v4f q = *(const v4f*)(w_query + (size_t)pos * H + h0);

    // ---- one-shot HBM read of this column's 16 value slices (streaming) ----
    v4f v[NBLK];
    const float* vbase = values + (size_t)bt * H + h0;
#pragma unroll
    for (int n = 0; n < NBLK; ++n)
        v[n] = __builtin_nontemporal_load((const v4f*)(vbase + (size_t)n * BT * H));

    // ---- per-thread partials -> LDS transpose ----
    // pv[n][t] = (sum v^2, sum q*v) partial of thread t for slot n.
    // b64 accesses: 2 lanes/bank-pair per 32-lane phase = 2-way = free (m136).
    __shared__ float2 pv[NBLK][256];   // 32 KiB exactly

#pragma unroll
    for (int n = 0; n < NBLK; ++n) {
        const v4f x  = v[n];
        const v4f xx = x * x;
        const v4f qx = q * x;
        const float ss = (xx[0] + xx[1]) + (xx[2] + xx[3]);
        const float qv = (qx[0] + qx[1]) + (qx[2] + qx[3]);
        pv[n][tid] = make_float2(ss, qv);
    }
    __syncthreads();

    // ---- transposed reduction: 16 contiguous lanes own slot n2 ----
    {
        const int n2 = tid >> 4;       // 0..15 (group of 16 lanes, wave-aligned)
        const int c  = tid & 15;
        float ss = 0.0f, qv = 0.0f;
#pragma unroll
        for (int k = 0; k < 16; ++k) {
            const float2 p = pv[n2][k * 16 + c];
            ss += p.x; qv += p.y;
        }
#pragma unroll
        for (int off = 1; off <= 8; off <<= 1) {  // 4-level, stays in 16-lane group
            ss += __shfl_xor(ss, off, 64);
            qv += __shfl_xor(qv, off, 64);
        }
        if (c == 0) {
            // pv[n2][0] is read only by this very lane (k=0,c=0) before the
            // intra-wave shuffle, so overwriting it here is race-free.
            const float inv = rsqrtf(ss * (1.0f / (float)H) + 1e-6f);
            pv[n2][0].x = (inv * qv + qb[n2]) * SCALE_INV;   // score_n
        }
    }
    __syncthreads();

    // ---- redundant per-thread softmax over 16 broadcast LDS scores ----
    float m = -3.402823466e38f;
#pragma unroll
    for (int n = 0; n < NBLK; ++n) m = fmaxf(m, pv[n][0].x);

    float a[NBLK];                     // static-indexed only -> stays in VGPRs
    float sum = 0.0f;
#pragma unroll
    for (int n = 0; n < NBLK; ++n) { a[n] = __expf(pv[n][0].x - m); sum += a[n]; }
    const float rs = 1.0f / sum;

    // ---- routed = sum_n alpha_n * v_n ----
    v4f acc = {0.0f, 0.0f, 0.0f, 0.0f};
#pragma unroll
    for (int n = 0; n < NBLK; ++n) acc += (a[n] * rs) * v[n];
    __builtin_nontemporal_store(acc, (v4f*)(out + (size_t)bt * H + h0));

    // ---- alpha_bth[b,t,n]: dynamic index goes to LDS, not a register array ----
    if (tid < NBLK)
        out[(size_t)ROUTED_SIZE + (size_t)bt * NBLK + tid]
            = __expf(pv[tid][0].x - m) * rs;
}

extern "C" void kernel_launch(void* const* d_in, const int* in_sizes, int n_in,
                              void* d_out, int out_size, void* d_ws, size_t ws_size,
                              hipStream_t stream) {
    const float* values       = (const float*)d_in[0];
    const float* w_query      = (const float*)d_in[1];
    const float* key_pos_bias = (const float*)d_in[2];
    const int*   position     = (const int*)d_in[3];
    float*       out          = (float*)d_out;
    float*       qb           = (float*)d_ws;   // 16 floats of scratch

    hipLaunchKernelGGL(qb_kernel, dim3(1), dim3(1024), 0, stream,
                       w_query, key_pos_bias, position, qb);
    hipLaunchKernelGGL(block_attn_res_kernel, dim3(BT), dim3(256), 0, stream,
                       values, w_query, position, qb, out);
}